// Round 6
// baseline (61.243 us; speedup 1.0000x reference)
//
#include <hip/hip_runtime.h>
#include <stdint.h>

#define HW   56
#define CH   64
#define PIX  (HW*HW)       // 3136
#define KS   7
#define PAD  3
#define TT   4             // 4x4 output tile
#define HALO 10            // TT + 2*PAD
#define HP   (HALO*HALO)   // 100 conv pixels per block
#define LD   68            // LDS row stride (floats): 16B-aligned rows, 2-way banks
#define NPT  7             // 7*16 = 112 >= 100 MFMA row-tiles

typedef __attribute__((ext_vector_type(8))) short short8;
typedef __attribute__((ext_vector_type(4))) float f32x4;

__device__ __forceinline__ uint32_t rne_bf16(float v) {
    uint32_t u = __float_as_uint(v);
    return (u + 0x7FFFu + ((u >> 16) & 1u)) >> 16;
}

// single fused kernel: grid 784 = 4 b * 14*14 tiles, block 256 (4 waves).
// LDS plan (floats): [0, 6800)  k  (aliases x-stage rows 0..99 in P1-P2)
//                    [6800,13600) v (x-stage rows 100..111 spill here: garbage-ok)
//                    [13600,14688) q (inner 16 px only)
__global__ __launch_bounds__(256) void fused_attn(
    const float* __restrict__ x,  const float* __restrict__ Wq,
    const float* __restrict__ Wk, const float* __restrict__ Wv,
    const float* __restrict__ rel_h, const float* __restrict__ rel_w,
    float* __restrict__ out)
{
    __shared__ float lds[2 * HP * LD + 16 * LD];   // 14688 floats = 58,752 B
    float* ks_ = lds;
    float* vs_ = lds + HP * LD;
    float* qs_ = lds + 2 * HP * LD;
    float* xs_ = lds;                              // alias (phases 1-2 only)

    const int t    = threadIdx.x;
    const int b    = blockIdx.x / 196;
    const int tile = blockIdx.x % 196;
    const int ty0  = (tile / 14) * TT;
    const int tx0  = (tile % 14) * TT;

    // ---- P1: stage x halo (fp32), rows of 10 via 16-lane units ----
    {
        const int hx   = t & 15;                   // 0..15, valid < 10
        const int unit = t >> 4;                   // 16 units
        const int gx   = tx0 + hx - PAD;
        const bool okx = (hx < HALO) & (gx >= 0) & (gx < HW);
        #pragma unroll
        for (int it = 0; it < 40; ++it) {
            int u  = unit + 16 * it;               // 0..639 = gy*64 + ci
            int gy = u >> 6;
            int ci = u & 63;
            int iy = ty0 + gy - PAD;
            float v = 0.f;
            if (okx & (iy >= 0) & (iy < HW))
                v = x[(b * CH + ci) * PIX + iy * HW + gx];
            if (hx < HALO)
                xs_[(gy * HALO + hx) * LD + ci] = v;
        }
    }
    __syncthreads();

    // ---- P2: A-fragments (x as split hi/lo bf16) into registers ----
    const int l  = t & 63;
    const int w  = t >> 6;                         // wave 0..3
    const int lr = l & 15;
    const int lk = l >> 4;

    short8 aH[2][2], aL[2][2];                     // [slot][k-chunk]
    #pragma unroll
    for (int i = 0; i < 2; ++i) {
        int pt = w + 4 * i;
        if (pt < NPT) {
            int arow = pt * 16 + lr;               // <= 111 (rows >=100 garbage-ok)
            #pragma unroll
            for (int ch = 0; ch < 2; ++ch) {
                const float* src = &xs_[arow * LD + ch * 32 + lk * 8];
                float4 f0 = *(const float4*)src;   // LD%4==0 -> 16B aligned
                float4 f1 = *(const float4*)(src + 4);
                float vv[8] = {f0.x, f0.y, f0.z, f0.w, f1.x, f1.y, f1.z, f1.w};
                short8 h, lo;
                #pragma unroll
                for (int j = 0; j < 8; ++j) {
                    uint32_t hb = rne_bf16(vv[j]);
                    h[j]  = (short)hb;
                    lo[j] = (short)rne_bf16(vv[j] - __uint_as_float(hb << 16));
                }
                aH[i][ch] = h; aL[i][ch] = lo;
            }
        }
    }
    __syncthreads();                               // xs dead; k/v may overwrite

    // ---- P3: k, v, q = x @ W^T via MFMA (W plain bf16; x split) ----
    #pragma unroll
    for (int m = 0; m < 3; ++m) {
        const float* __restrict__ Wm = (m == 0) ? Wk : (m == 1) ? Wv : Wq;
        short8 bh[4][2];
        #pragma unroll
        for (int cot = 0; cot < 4; ++cot) {
            #pragma unroll
            for (int ch = 0; ch < 2; ++ch) {
                const float* src = &Wm[(cot * 16 + lr) * 64 + ch * 32 + lk * 8];
                float4 f0 = *(const float4*)src;
                float4 f1 = *(const float4*)(src + 4);
                short8 h;
                h[0] = (short)rne_bf16(f0.x); h[1] = (short)rne_bf16(f0.y);
                h[2] = (short)rne_bf16(f0.z); h[3] = (short)rne_bf16(f0.w);
                h[4] = (short)rne_bf16(f1.x); h[5] = (short)rne_bf16(f1.y);
                h[6] = (short)rne_bf16(f1.z); h[7] = (short)rne_bf16(f1.w);
                bh[cot][ch] = h;
            }
        }
        #pragma unroll
        for (int i = 0; i < 2; ++i) {
            int pt = w + 4 * i;
            if (pt < NPT) {
                #pragma unroll
                for (int cot = 0; cot < 4; ++cot) {
                    f32x4 a = {0.f, 0.f, 0.f, 0.f};
                    a = __builtin_amdgcn_mfma_f32_16x16x32_bf16(aL[i][0], bh[cot][0], a, 0, 0, 0);
                    a = __builtin_amdgcn_mfma_f32_16x16x32_bf16(aH[i][0], bh[cot][0], a, 0, 0, 0);
                    a = __builtin_amdgcn_mfma_f32_16x16x32_bf16(aL[i][1], bh[cot][1], a, 0, 0, 0);
                    a = __builtin_amdgcn_mfma_f32_16x16x32_bf16(aH[i][1], bh[cot][1], a, 0, 0, 0);
                    const int co = cot * 16 + lr;
                    #pragma unroll
                    for (int r = 0; r < 4; ++r) {
                        int px = pt * 16 + lk * 4 + r;
                        if (px < HP) {
                            if (m == 0)      ks_[px * LD + co] = a[r];
                            else if (m == 1) vs_[px * LD + co] = a[r];
                            else {
                                int py = px / 10, pxx = px % 10;
                                if (py >= PAD && py < PAD + TT &&
                                    pxx >= PAD && pxx < PAD + TT)
                                    qs_[((py - PAD) * TT + (pxx - PAD)) * LD + co] = a[r];
                            }
                        }
                    }
                }
            }
        }
    }
    __syncthreads();

    // ---- P4: per-channel windowed attention ----
    const int c  = l;
    const int oy = w;                              // 0..3
    const bool is_h = (c < 32);
    float relv[KS];
    #pragma unroll
    for (int j = 0; j < KS; ++j)
        relv[j] = is_h ? rel_h[c * KS + j] : rel_w[(c - 32) * KS + j];

    float qv[TT], sum[TT], acc[TT];
    #pragma unroll
    for (int ox = 0; ox < TT; ++ox) {
        qv[ox] = qs_[(oy * TT + ox) * LD + c];
        sum[ox] = 0.f; acc[ox] = 0.f;
    }

    #pragma unroll
    for (int kh = 0; kh < KS; ++kh) {
        float kr[HALO], vr[HALO];                  // halo row once, reused by 4 ox
        const int rb = (oy + kh) * HALO;
        #pragma unroll
        for (int ii = 0; ii < HALO; ++ii) {
            kr[ii] = ks_[(rb + ii) * LD + c];
            vr[ii] = vs_[(rb + ii) * LD + c];
        }
        const float rh = relv[kh];
        #pragma unroll
        for (int ox = 0; ox < TT; ++ox) {
            #pragma unroll
            for (int kw = 0; kw < KS; ++kw) {
                float e = __expf(qv[ox] * kr[ox + kw]);
                sum[ox] += e;
                acc[ox] = fmaf(e, vr[ox + kw] + (is_h ? rh : relv[kw]), acc[ox]);
            }
        }
    }

    // ---- P5: LDS transpose + coalesced BCHW store ----
    __syncthreads();                               // k/v reads done
    float* os = lds;                               // reuse k region
    #pragma unroll
    for (int ox = 0; ox < TT; ++ox)
        os[(oy * TT + ox) * LD + c] = acc[ox] / sum[ox];
    __syncthreads();
    #pragma unroll
    for (int k2 = 0; k2 < 4; ++k2) {
        int idx = t + k2 * 256;                    // 0..1023 = cc*16 + p
        int p   = idx & 15;
        int cc  = idx >> 4;
        out[(b * CH + cc) * PIX + (ty0 + (p >> 2)) * HW + tx0 + (p & 3)] =
            os[p * LD + cc];
    }
}

extern "C" void kernel_launch(void* const* d_in, const int* in_sizes, int n_in,
                              void* d_out, int out_size, void* d_ws, size_t ws_size,
                              hipStream_t stream) {
    const float* x     = (const float*)d_in[0];
    const float* Wq    = (const float*)d_in[1];
    const float* Wk    = (const float*)d_in[2];
    const float* Wv    = (const float*)d_in[3];
    const float* rel_h = (const float*)d_in[4];
    const float* rel_w = (const float*)d_in[5];
    float* out = (float*)d_out;

    fused_attn<<<784, 256, 0, stream>>>(x, Wq, Wk, Wv, rel_h, rel_w, out);
}

// Round 7
// 23.393 us; speedup vs baseline: 2.6180x; 2.6180x over previous
//
#include <hip/hip_runtime.h>
#include <stdint.h>

#define HW    56
#define CH    64
#define PIX   (HW*HW)      // 3136
#define KS    7
#define PAD   3
#define TS    8            // 8x8 output tile
#define HALO  14
#define HP    (HALO*HALO)  // 196
#define NPT   13           // ceil(196/16)
#define XLD   68           // xs/qs float stride
#define KVLD  67           // kv float2 stride (2-way banks)

// LDS float offsets
#define OFF_QS  26264      // after kv: 196*67 float2 = 26264 floats
#define OFF_W   30616      // after qs: 64*68 = 4352 floats
#define OFF_REL 36760      // after W: 1536 short8 = 6144 floats
#define LDS_F   37208      // total floats = 148,832 B

typedef __attribute__((ext_vector_type(8))) short short8;
typedef __attribute__((ext_vector_type(4))) float f32x4;

__device__ __forceinline__ uint32_t rne_bf16(float v) {
    uint32_t u = __float_as_uint(v);
    return (u + 0x7FFFu + ((u >> 16) & 1u)) >> 16;
}
__device__ __forceinline__ float fexp2(float x) {
    float r;
    asm("v_exp_f32 %0, %1" : "=v"(r) : "v"(x));
    return r;
}

// single fused kernel: grid 196 = 4 b * 7*7 tiles of 8x8, block 1024 (16 waves)
__global__ __launch_bounds__(1024) void fused_attn(
    const float* __restrict__ x,  const float* __restrict__ Wq,
    const float* __restrict__ Wk, const float* __restrict__ Wv,
    const float* __restrict__ rel_h, const float* __restrict__ rel_w,
    float* __restrict__ out)
{
    __shared__ __align__(16) float lds[LDS_F];
    float2* kv   = (float2*)lds;            // [px][c] stride KVLD (aliases xs)
    float*  xs   = lds;                     // x halo [px][ci] stride XLD (P1-P2)
    float*  qs   = lds + OFF_QS;            // q inner [ip][c] stride XLD
    short8* wlds = (short8*)(lds + OFF_W);  // W bf16 frags [1536]
    float*  rlds = lds + OFF_REL;           // rel_h(224) ++ rel_w(224)

    const int t    = threadIdx.x;
    const int b    = blockIdx.x / 49;
    const int tile = blockIdx.x % 49;
    const int ty0  = (tile / 7) * TS;
    const int tx0  = (tile % 7) * TS;

    // ---- P1: stage x halo (fp32), W (bf16 frag order), rel ----
    {
        const int hx = t & 15;
        const int ci = t >> 4;             // 0..63
        const int gx = tx0 + hx - PAD;
        const bool okx = (hx < HALO) & (gx >= 0) & (gx < HW);
        const float* xb = x + (size_t)(b * CH + ci) * PIX;
        #pragma unroll
        for (int it = 0; it < HALO; ++it) {
            int gy = ty0 + it - PAD;       // wave-uniform row validity
            bool ok = okx & (gy >= 0) & (gy < HW);
            float v = ok ? xb[gy * HW + gx] : 0.f;
            if (hx < HALO)
                xs[(it * HALO + hx) * XLD + ci] = v;
        }
    }
    if (t < 768)                           // zero pad rows 196..207
        xs[(HP + (t >> 6)) * XLD + (t & 63)] = 0.f;
    #pragma unroll
    for (int k = 0; k < 2; ++k) {          // W -> bf16 fragments (once)
        int u = t + k * 1024;
        if (u < 1536) {
            int m = u >> 9, cot = (u >> 7) & 3, ch = (u >> 6) & 1, l2 = u & 63;
            const float* Wm = (m == 0) ? Wk : (m == 1) ? Wv : Wq;
            const float* src = &Wm[(cot * 16 + (l2 & 15)) * 64 + ch * 32 + (l2 >> 4) * 8];
            float4 f0 = *(const float4*)src;
            float4 f1 = *(const float4*)(src + 4);
            short8 h;
            h[0] = (short)rne_bf16(f0.x); h[1] = (short)rne_bf16(f0.y);
            h[2] = (short)rne_bf16(f0.z); h[3] = (short)rne_bf16(f0.w);
            h[4] = (short)rne_bf16(f1.x); h[5] = (short)rne_bf16(f1.y);
            h[6] = (short)rne_bf16(f1.z); h[7] = (short)rne_bf16(f1.w);
            wlds[u] = h;
        }
    }
    if (t < 448)
        rlds[t] = (t < 224) ? rel_h[t] : rel_w[t - 224];
    __syncthreads();

    // ---- P2: A-fragments (x split hi/lo bf16) into registers ----
    const int l  = t & 63;
    const int w  = t >> 6;                 // wave 0..15
    const int lr = l & 15;
    const int lk = l >> 4;

    short8 aH[2], aL[2];
    if (w < NPT) {
        int arow = w * 16 + lr;
        #pragma unroll
        for (int ch = 0; ch < 2; ++ch) {
            const float* src = &xs[arow * XLD + ch * 32 + lk * 8];
            float4 f0 = *(const float4*)src;
            float4 f1 = *(const float4*)(src + 4);
            float vv[8] = {f0.x, f0.y, f0.z, f0.w, f1.x, f1.y, f1.z, f1.w};
            short8 h, lo;
            #pragma unroll
            for (int j = 0; j < 8; ++j) {
                uint32_t hb = rne_bf16(vv[j]);
                h[j]  = (short)hb;
                lo[j] = (short)rne_bf16(vv[j] - __uint_as_float(hb << 16));
            }
            aH[ch] = h; aL[ch] = lo;
        }
    }
    __syncthreads();                       // xs dead; kv may overwrite

    // ---- P3: k, v, q via MFMA (W bf16 from LDS; x split) ----
    #pragma unroll
    for (int m = 0; m < 3; ++m) {
        if (w < NPT) {
            short8 bh[4][2];
            #pragma unroll
            for (int cot = 0; cot < 4; ++cot)
                #pragma unroll
                for (int ch = 0; ch < 2; ++ch)
                    bh[cot][ch] = wlds[((m * 4 + cot) * 2 + ch) * 64 + l];
            #pragma unroll
            for (int cot = 0; cot < 4; ++cot) {
                f32x4 a = {0.f, 0.f, 0.f, 0.f};
                a = __builtin_amdgcn_mfma_f32_16x16x32_bf16(aL[0], bh[cot][0], a, 0, 0, 0);
                a = __builtin_amdgcn_mfma_f32_16x16x32_bf16(aH[0], bh[cot][0], a, 0, 0, 0);
                a = __builtin_amdgcn_mfma_f32_16x16x32_bf16(aL[1], bh[cot][1], a, 0, 0, 0);
                a = __builtin_amdgcn_mfma_f32_16x16x32_bf16(aH[1], bh[cot][1], a, 0, 0, 0);
                const int co = cot * 16 + lr;
                #pragma unroll
                for (int r = 0; r < 4; ++r) {
                    int px = w * 16 + lk * 4 + r;
                    if (px < HP) {
                        if (m == 0)      kv[px * KVLD + co].x = a[r];
                        else if (m == 1) kv[px * KVLD + co].y = a[r];
                        else {
                            int py = px / HALO, pxx = px % HALO;
                            if (py >= PAD && py < PAD + TS &&
                                pxx >= PAD && pxx < PAD + TS)
                                qs[((py - PAD) * TS + (pxx - PAD)) * XLD + co] = a[r];
                        }
                    }
                }
            }
        }
    }
    __syncthreads();

    // ---- P4: per-channel windowed attention ----
    // remap so is_h is wave-uniform: c = (w&1)*32 + (l&31)
    const int c    = ((w & 1) << 5) | (l & 31);
    const int quad = ((w >> 1) << 1) | (l >> 5);   // 0..15
    const int oy   = quad & 7;
    const int half = quad >> 3;                    // 0..1 -> ox base
    const bool is_h = ((w & 1) == 0);

    float relv[KS];
    #pragma unroll
    for (int j = 0; j < KS; ++j)
        relv[j] = rlds[(is_h ? 0 : 224) + (c & 31) * KS + j];

    float qv[4], sum[4], acc[4], racc[4];
    #pragma unroll
    for (int ox = 0; ox < 4; ++ox) {
        qv[ox] = qs[(oy * TS + half * 4 + ox) * XLD + c] * 1.44269504088896f;
        sum[ox] = 0.f; acc[ox] = 0.f; racc[ox] = 0.f;
    }

    #pragma unroll
    for (int kh = 0; kh < KS; ++kh) {
        const int prow0 = (oy + kh) * HALO + half * 4;
        float2 row[10];
        #pragma unroll
        for (int ii = 0; ii < 10; ++ii)
            row[ii] = kv[(prow0 + ii) * KVLD + c];
        const float rh = relv[kh];
        if (is_h) {                        // wave-uniform branch
            #pragma unroll
            for (int ox = 0; ox < 4; ++ox) {
                float esum = 0.f;
                #pragma unroll
                for (int kw = 0; kw < KS; ++kw) {
                    float2 f = row[ox + kw];
                    float e = fexp2(qv[ox] * f.x);
                    esum += e;
                    acc[ox] = fmaf(e, f.y, acc[ox]);
                }
                sum[ox] += esum;
                racc[ox] = fmaf(rh, esum, racc[ox]);
            }
        } else {
            #pragma unroll
            for (int ox = 0; ox < 4; ++ox) {
                #pragma unroll
                for (int kw = 0; kw < KS; ++kw) {
                    float2 f = row[ox + kw];
                    float e = fexp2(qv[ox] * f.x);
                    sum[ox] += e;
                    acc[ox]  = fmaf(e, f.y, acc[ox]);
                    racc[ox] = fmaf(e, relv[kw], racc[ox]);
                }
            }
        }
    }
    __syncthreads();                       // kv/qs reads done

    // ---- P5: transpose via LDS (reuse qs region) + coalesced BCHW store ----
    float* os = qs;
    #pragma unroll
    for (int ox = 0; ox < 4; ++ox)
        os[(oy * TS + half * 4 + ox) * XLD + c] =
            (acc[ox] + racc[ox]) * __builtin_amdgcn_rcpf(sum[ox]);
    __syncthreads();
    #pragma unroll
    for (int k2 = 0; k2 < 4; ++k2) {
        int idx = t + 1024 * k2;           // 0..4095 = cc*64 + p
        int p   = idx & 63;
        int cc  = idx >> 6;
        out[(b * CH + cc) * PIX + (ty0 + (p >> 3)) * HW + tx0 + (p & 7)] =
            os[p * XLD + cc];
    }
}

extern "C" void kernel_launch(void* const* d_in, const int* in_sizes, int n_in,
                              void* d_out, int out_size, void* d_ws, size_t ws_size,
                              hipStream_t stream) {
    const float* x     = (const float*)d_in[0];
    const float* Wq    = (const float*)d_in[1];
    const float* Wk    = (const float*)d_in[2];
    const float* Wv    = (const float*)d_in[3];
    const float* rel_h = (const float*)d_in[4];
    const float* rel_w = (const float*)d_in[5];
    float* out = (float*)d_out;

    fused_attn<<<196, 1024, 0, stream>>>(x, Wq, Wk, Wv, rel_h, rel_w, out);
}